// Round 1
// baseline (227.453 us; speedup 1.0000x reference)
//
#include <hip/hip_runtime.h>

#define NROWS 8192
#define DDIM  1024

typedef short  bf16x8 __attribute__((ext_vector_type(8)));  // 8 bf16 in 4 VGPRs
typedef float  f32x4  __attribute__((ext_vector_type(4)));
typedef unsigned short ushort_t;

// ---- round-to-nearest-even fp32 -> bf16 (bit pattern in ushort) ----
__device__ __forceinline__ ushort_t f2bf(float f) {
    union { float f; unsigned u; } v; v.f = f;
    unsigned r = v.u + 0x7fffu + ((v.u >> 16) & 1u);
    return (ushort_t)(r >> 16);
}

// async global->LDS, 16B per lane, linear LDS dest (wave-uniform base + lane*16)
#define GLD(gp, lp)                                                        \
    __builtin_amdgcn_global_load_lds(                                      \
        (const __attribute__((address_space(1))) void*)(gp),               \
        (__attribute__((address_space(3))) void*)(lp), 16, 0, 0)

// ============================================================================
// Kernel 1: row L2-normalize fp32 -> bf16.  One block (256t) per row.
// ============================================================================
__global__ __launch_bounds__(256) void snnl_normalize(
    const float* __restrict__ x, ushort_t* __restrict__ xn)
{
    const int row = (int)blockIdx.x;
    const int tid = (int)threadIdx.x;
    const float4 v = ((const float4*)(x + (size_t)row * DDIM))[tid];
    float ss = v.x * v.x + v.y * v.y + v.z * v.z + v.w * v.w;
#pragma unroll
    for (int m = 32; m >= 1; m >>= 1) ss += __shfl_xor(ss, m);
    __shared__ float ws4[4];
    if ((tid & 63) == 0) ws4[tid >> 6] = ss;
    __syncthreads();
    const float tot = ws4[0] + ws4[1] + ws4[2] + ws4[3];
    const float inv = 1.0f / fmaxf(sqrtf(tot), 1e-8f);   // COS_EPS clamp
    ushort4 o;
    o.x = f2bf(v.x * inv);
    o.y = f2bf(v.y * inv);
    o.z = f2bf(v.z * inv);
    o.w = f2bf(v.w * inv);
    ((ushort4*)(xn + (size_t)row * DDIM))[tid] = o;
}

// ============================================================================
// Kernel 2: fused sim-GEMM + exp + masked row-sums.
//  Tile 128(i) x 128(j), BK=64, 4 waves in 2x2, each wave 64x64 out.
//  Block handles 4 j-tiles (512 cols); grid = (8192/128) x (8192/512) = 64x16.
//  LDS tiles XOR-swizzled (byte ^= (row&7)<<4) via pre-swizzled global source
//  (global_load_lds writes linearly) + swizzled ds_read -> conflict-free b128.
// ============================================================================
__global__ __launch_bounds__(256, 2) void snnl_main(
    const ushort_t* __restrict__ xn, const int* __restrict__ y,
    const float* __restrict__ T,
    float* __restrict__ top, float* __restrict__ bot)
{
    __shared__ char smem[32768];          // A tile 16KB | B tile 16KB
    __shared__ int  yrow_s[128];
    __shared__ int  ycol_s[512];

    const int tid  = (int)threadIdx.x;
    const int lane = tid & 63;
    const int w    = tid >> 6;
    const int wr   = w >> 1;              // wave row (0..1) -> 64 output rows
    const int wc   = w & 1;               // wave col (0..1) -> 64 output cols
    const int i0   = (int)blockIdx.x * 128;
    const int j0   = (int)blockIdx.y * 512;

    if (tid < 128) yrow_s[tid] = y[i0 + tid];
    ycol_s[tid]        = y[j0 + tid];
    ycol_s[tid + 256]  = y[j0 + 256 + tid];

    const float invT = 1.0f / T[0];

    // --- staging constants: thread t writes LDS bytes [q*4096 + t*16, +16) ---
    // LDS linear offset o: row = o>>7 (tile row), col byte = o&127.
    // Swizzle (involution): stored col = col ^ ((row&7)<<4).
    const int  rr  = tid >> 3;                               // tile row % 32
    const int  scb = (((tid & 7) ^ (rr & 7)) << 4);          // source col byte
    const char* const xb = (const char*)xn;

    // --- fragment-read constants (read side applies the same XOR) ---
    // A frag (mi): row = wr*64+mi*16+(lane&15); col byte = ks*64+((lane>>4)<<4)
    const int c0 = (((lane >> 4) << 4)) ^ ((lane & 7) << 4);
    int arow[4], brow[4];
#pragma unroll
    for (int mi = 0; mi < 4; ++mi) arow[mi] = (wr * 64 + mi * 16 + (lane & 15)) * 128;
#pragma unroll
    for (int ni = 0; ni < 4; ++ni) brow[ni] = 16384 + (wc * 64 + ni * 16 + (lane & 15)) * 128;

    float tsum[4][4], bsum[4][4];
#pragma unroll
    for (int mi = 0; mi < 4; ++mi)
#pragma unroll
        for (int r = 0; r < 4; ++r) { tsum[mi][r] = 0.0f; bsum[mi][r] = 0.0f; }

    const f32x4 zero4 = {0.0f, 0.0f, 0.0f, 0.0f};

    for (int jtl = 0; jtl < 4; ++jtl) {
        const int jb = j0 + jtl * 128;

        f32x4 acc[4][4];
#pragma unroll
        for (int mi = 0; mi < 4; ++mi)
#pragma unroll
            for (int ni = 0; ni < 4; ++ni) acc[mi][ni] = zero4;

        for (int kt = 0; kt < 16; ++kt) {
            const size_t kb = ((size_t)kt << 7) + (size_t)scb;
            // stage A (rows i0..i0+127) and B (rows jb..jb+127), k-slice kt*64
#pragma unroll
            for (int q = 0; q < 4; ++q)
                GLD(xb + (((size_t)(i0 + q * 32 + rr)) << 11) + kb,
                    smem + (q << 12) + (tid << 4));
#pragma unroll
            for (int q = 0; q < 4; ++q)
                GLD(xb + (((size_t)(jb + q * 32 + rr)) << 11) + kb,
                    smem + 16384 + (q << 12) + (tid << 4));
            __syncthreads();   // compiler drains vmcnt before s_barrier

#pragma unroll
            for (int ks = 0; ks < 2; ++ks) {
                const int cks = c0 ^ (ks << 6);
                bf16x8 af[4], bfr[4];
#pragma unroll
                for (int mi = 0; mi < 4; ++mi)
                    af[mi] = *(const bf16x8*)(smem + arow[mi] + cks);
#pragma unroll
                for (int ni = 0; ni < 4; ++ni)
                    bfr[ni] = *(const bf16x8*)(smem + brow[ni] + cks);
#pragma unroll
                for (int mi = 0; mi < 4; ++mi)
#pragma unroll
                    for (int ni = 0; ni < 4; ++ni)
                        acc[mi][ni] = __builtin_amdgcn_mfma_f32_16x16x32_bf16(
                            af[mi], bfr[ni], acc[mi][ni], 0, 0, 0);
            }
            __syncthreads();
        }

        // ---- fused epilogue: f = exp((sim-1)/T), masked row accumulation ----
        const int jl0 = jtl * 128 + wc * 64;
        int yjv[4], jgv[4];
#pragma unroll
        for (int ni = 0; ni < 4; ++ni) {
            const int jloc = jl0 + ni * 16 + (lane & 15);
            yjv[ni] = ycol_s[jloc];
            jgv[ni] = j0 + jloc;
        }
#pragma unroll
        for (int mi = 0; mi < 4; ++mi) {
#pragma unroll
            for (int r = 0; r < 4; ++r) {
                const int il = wr * 64 + mi * 16 + ((lane >> 4) << 2) + r;
                const int ig = i0 + il;
                const int yi = yrow_s[il];
                float ba = 0.0f, ta = 0.0f;
#pragma unroll
                for (int ni = 0; ni < 4; ++ni) {
                    const float fv = __expf((acc[mi][ni][r] - 1.0f) * invT);
                    const float bv = (ig != jgv[ni]) ? fv : 0.0f;  // off-diag
                    ba += bv;
                    ta += (yi == yjv[ni]) ? bv : 0.0f;             // same-label
                }
                bsum[mi][r] += ba;
                tsum[mi][r] += ta;
            }
        }
    }

    // ---- reduce across the 16 lanes that share a row, then one atomic ----
#pragma unroll
    for (int mi = 0; mi < 4; ++mi) {
#pragma unroll
        for (int r = 0; r < 4; ++r) {
            float t = tsum[mi][r];
            float b = bsum[mi][r];
            t += __shfl_xor(t, 1); t += __shfl_xor(t, 2);
            t += __shfl_xor(t, 4); t += __shfl_xor(t, 8);
            b += __shfl_xor(b, 1); b += __shfl_xor(b, 2);
            b += __shfl_xor(b, 4); b += __shfl_xor(b, 8);
            if ((lane & 15) == 0) {
                const int ig = i0 + wr * 64 + mi * 16 + ((lane >> 4) << 2) + r;
                atomicAdd(&top[ig], t);
                atomicAdd(&bot[ig], b);
            }
        }
    }
}

// ============================================================================
// Kernel 3: loss = -mean(log((top+1e-9)/bot))
// ============================================================================
__global__ __launch_bounds__(1024) void snnl_loss(
    const float* __restrict__ top, const float* __restrict__ bot,
    float* __restrict__ out)
{
    const int tid = (int)threadIdx.x;
    float s = 0.0f;
    for (int i = tid; i < NROWS; i += 1024)
        s += __logf((top[i] + 1e-9f) / bot[i]);
#pragma unroll
    for (int m = 32; m >= 1; m >>= 1) s += __shfl_xor(s, m);
    __shared__ float ws16[16];
    if ((tid & 63) == 0) ws16[tid >> 6] = s;
    __syncthreads();
    if (tid == 0) {
        float tot = 0.0f;
#pragma unroll
        for (int k = 0; k < 16; ++k) tot += ws16[k];
        out[0] = -tot / (float)NROWS;
    }
}

// ============================================================================
extern "C" void kernel_launch(void* const* d_in, const int* in_sizes, int n_in,
                              void* d_out, int out_size, void* d_ws, size_t ws_size,
                              hipStream_t stream)
{
    const float* x = (const float*)d_in[0];
    const int*   y = (const int*)d_in[1];
    const float* T = (const float*)d_in[2];
    float* out = (float*)d_out;

    char* ws = (char*)d_ws;
    ushort_t* xn  = (ushort_t*)ws;                              // 16 MiB bf16 Xn
    float*    top = (float*)(ws + (size_t)16 * 1024 * 1024);    // 32 KiB
    float*    bot = top + NROWS;                                // 32 KiB

    hipMemsetAsync(top, 0, 2 * NROWS * sizeof(float), stream);  // zero top+bot
    snnl_normalize<<<NROWS, 256, 0, stream>>>(x, xn);
    snnl_main<<<dim3(64, 16), 256, 0, stream>>>(xn, y, T, top, bot);
    snnl_loss<<<1, 1024, 0, stream>>>(top, bot, out);
}

// Round 4
// 218.494 us; speedup vs baseline: 1.0410x; 1.0410x over previous
//
#include <hip/hip_runtime.h>

#define NROWS 8192
#define DDIM  1024
#define NTILE 64                      // 8192 / 128 tiles per dim
#define NTRI  2080                    // NTILE*(NTILE+1)/2 upper-triangle tiles

typedef short  bf16x8 __attribute__((ext_vector_type(8)));  // 8 bf16 in 4 VGPRs
typedef float  f32x4  __attribute__((ext_vector_type(4)));
typedef unsigned short ushort_t;

// ---- round-to-nearest-even fp32 -> bf16 (bit pattern in ushort) ----
__device__ __forceinline__ ushort_t f2bf(float f) {
    union { float f; unsigned u; } v; v.f = f;
    unsigned r = v.u + 0x7fffu + ((v.u >> 16) & 1u);
    return (ushort_t)(r >> 16);
}

// async global->LDS, 16B per lane, linear LDS dest (wave-uniform base + lane*16)
#define GLD(gp, lp)                                                        \
    __builtin_amdgcn_global_load_lds(                                      \
        (const __attribute__((address_space(1))) void*)(gp),               \
        (__attribute__((address_space(3))) void*)(lp), 16, 0, 0)

// ============================================================================
// Kernel 1: row L2-normalize fp32 -> bf16. One block (256t) per row.
// Also zeroes top/bot (and out) so no separate memset dispatch is needed.
// ============================================================================
__global__ __launch_bounds__(256) void snnl_normalize(
    const float* __restrict__ x, ushort_t* __restrict__ xn,
    float* __restrict__ top, float* __restrict__ bot, float* __restrict__ out)
{
    const int row = (int)blockIdx.x;
    const int tid = (int)threadIdx.x;
    if (tid == 0) {
        top[row] = 0.0f;
        bot[row] = 0.0f;
        if (row == 0) out[0] = 0.0f;
    }
    const float4 v = ((const float4*)(x + (size_t)row * DDIM))[tid];
    float ss = v.x * v.x + v.y * v.y + v.z * v.z + v.w * v.w;
#pragma unroll
    for (int m = 32; m >= 1; m >>= 1) ss += __shfl_xor(ss, m);
    __shared__ float ws4[4];
    if ((tid & 63) == 0) ws4[tid >> 6] = ss;
    __syncthreads();
    const float tot = ws4[0] + ws4[1] + ws4[2] + ws4[3];
    const float inv = 1.0f / fmaxf(sqrtf(tot), 1e-8f);   // COS_EPS clamp
    ushort4 o;
    o.x = f2bf(v.x * inv);
    o.y = f2bf(v.y * inv);
    o.z = f2bf(v.z * inv);
    o.w = f2bf(v.w * inv);
    ((ushort4*)(xn + (size_t)row * DDIM))[tid] = o;
}

// ============================================================================
// Kernel 2: fused sim-GEMM + exp + masked row/col sums, UPPER TRIANGLE ONLY.
//  sim is bit-exact symmetric (same products, same k-order), so tile (bi,bj)
//  with bi<bj also supplies the (bj,bi) tile via column sums. Diagonal tiles
//  do the row pass only (both (i,j) and (j,i) live in the tile).
//  Tile 128(i) x 128(j), BK=64, 4 waves in 2x2, each wave 64x64 out.
//  LDS XOR-swizzled (byte ^= (row&7)<<4) via pre-swizzled global source
//  (global_load_lds writes linearly) + swizzled ds_read -> conflict-free b128.
// ============================================================================
__global__ __launch_bounds__(256, 2) void snnl_main(
    const ushort_t* __restrict__ xn, const int* __restrict__ y,
    const float* __restrict__ T,
    float* __restrict__ top, float* __restrict__ bot)
{
    __shared__ char smem[32768];          // A tile 16KB | B tile 16KB
    __shared__ int  yrow_s[128];
    __shared__ int  ycol_s[128];

    // ---- XCD-aware swizzle (2080 % 8 == 0 -> simple bijective form) ----
    const int bid = (int)blockIdx.x;
    const int t   = (bid & 7) * (NTRI / 8) + (bid >> 3);

    // ---- invert triangular index: t -> (bi, bj), bi <= bj ----
    // start(b) = b*NTILE - b*(b-1)/2
#define TSTART(b) ((b) * NTILE - (b) * ((b) - 1) / 2)
    int bi = (int)(0.5f * (129.0f - sqrtf(129.0f * 129.0f - 8.0f * (float)t)));
    if (bi < 0) bi = 0;
    if (bi > NTILE - 1) bi = NTILE - 1;
    while (bi > 0 && TSTART(bi) > t) --bi;
    while (bi < NTILE - 1 && TSTART(bi + 1) <= t) ++bi;
    const int bj = bi + (t - TSTART(bi));
    const bool offdiag = (bi != bj);

    const int tid  = (int)threadIdx.x;
    const int lane = tid & 63;
    const int w    = tid >> 6;
    const int wr   = w >> 1;              // wave row (0..1) -> 64 output rows
    const int wc   = w & 1;               // wave col (0..1) -> 64 output cols
    const int i0   = bi * 128;
    const int j0   = bj * 128;

    if (tid < 128)       yrow_s[tid] = y[i0 + tid];
    else                 ycol_s[tid - 128] = y[j0 + tid - 128];

    const float invT = 1.0f / T[0];

    // --- staging constants: thread tt writes LDS bytes [q*4096 + tt*16, +16) ---
    // LDS linear offset o: row = o>>7 (tile row), col byte = o&127.
    // Swizzle (involution): stored col = col ^ ((row&7)<<4).
    const int  rr  = tid >> 3;                               // tile row % 32
    const int  scb = (((tid & 7) ^ (rr & 7)) << 4);          // source col byte
    const char* const xb = (const char*)xn;

    // --- fragment-read constants (read side applies the same XOR) ---
    const int c0 = (((lane >> 4) << 4)) ^ ((lane & 7) << 4);
    int arow[4], brow[4];
#pragma unroll
    for (int mi = 0; mi < 4; ++mi) arow[mi] = (wr * 64 + mi * 16 + (lane & 15)) * 128;
#pragma unroll
    for (int ni = 0; ni < 4; ++ni) brow[ni] = 16384 + (wc * 64 + ni * 16 + (lane & 15)) * 128;

    const f32x4 zero4 = {0.0f, 0.0f, 0.0f, 0.0f};
    f32x4 acc[4][4];
#pragma unroll
    for (int mi = 0; mi < 4; ++mi)
#pragma unroll
        for (int ni = 0; ni < 4; ++ni) acc[mi][ni] = zero4;

    for (int kt = 0; kt < 16; ++kt) {
        const size_t kb = ((size_t)kt << 7) + (size_t)scb;
#pragma unroll
        for (int q = 0; q < 4; ++q)
            GLD(xb + (((size_t)(i0 + q * 32 + rr)) << 11) + kb,
                smem + (q << 12) + (tid << 4));
#pragma unroll
        for (int q = 0; q < 4; ++q)
            GLD(xb + (((size_t)(j0 + q * 32 + rr)) << 11) + kb,
                smem + 16384 + (q << 12) + (tid << 4));
        __syncthreads();   // compiler drains vmcnt before s_barrier

#pragma unroll
        for (int ks = 0; ks < 2; ++ks) {
            const int cks = c0 ^ (ks << 6);
            bf16x8 af[4], bfr[4];
#pragma unroll
            for (int mi = 0; mi < 4; ++mi)
                af[mi] = *(const bf16x8*)(smem + arow[mi] + cks);
#pragma unroll
            for (int ni = 0; ni < 4; ++ni)
                bfr[ni] = *(const bf16x8*)(smem + brow[ni] + cks);
#pragma unroll
            for (int mi = 0; mi < 4; ++mi)
#pragma unroll
                for (int ni = 0; ni < 4; ++ni)
                    acc[mi][ni] = __builtin_amdgcn_mfma_f32_16x16x32_bf16(
                        af[mi], bfr[ni], acc[mi][ni], 0, 0, 0);
        }
        __syncthreads();
    }

    // ---- fused epilogue: f = exp((sim-1)/T), masked row AND col sums ----
    int yjv[4], jgv[4];
#pragma unroll
    for (int ni = 0; ni < 4; ++ni) {
        const int jloc = wc * 64 + ni * 16 + (lane & 15);
        yjv[ni] = ycol_s[jloc];
        jgv[ni] = j0 + jloc;
    }
    float ct[4], cb[4];                       // column accumulators (per ni)
#pragma unroll
    for (int ni = 0; ni < 4; ++ni) { ct[ni] = 0.0f; cb[ni] = 0.0f; }

#pragma unroll
    for (int mi = 0; mi < 4; ++mi) {
#pragma unroll
        for (int r = 0; r < 4; ++r) {
            const int il = wr * 64 + mi * 16 + ((lane >> 4) << 2) + r;
            const int ig = i0 + il;
            const int yi = yrow_s[il];
            float ba = 0.0f, ta = 0.0f;
#pragma unroll
            for (int ni = 0; ni < 4; ++ni) {
                const float fv = __expf((acc[mi][ni][r] - 1.0f) * invT);
                const bool  sm = (yi == yjv[ni]);
                const float bv = (ig != jgv[ni]) ? fv : 0.0f;   // off-diag mask
                const float tv = sm ? bv : 0.0f;                // same-label
                ba += bv;  ta += tv;
                cb[ni] += bv;  ct[ni] += tv;                    // transposed tile
            }
            // row reduce across the 16 lanes sharing this row, one atomic
            ta += __shfl_xor(ta, 1); ta += __shfl_xor(ta, 2);
            ta += __shfl_xor(ta, 4); ta += __shfl_xor(ta, 8);
            ba += __shfl_xor(ba, 1); ba += __shfl_xor(ba, 2);
            ba += __shfl_xor(ba, 4); ba += __shfl_xor(ba, 8);
            if ((lane & 15) == 0) {
                atomicAdd(&top[ig], ta);
                atomicAdd(&bot[ig], ba);
            }
        }
    }

    if (offdiag) {
        // col reduce: col = lane&15 fixed, sum the 4 lane-quarters
#pragma unroll
        for (int ni = 0; ni < 4; ++ni) {
            float tv = ct[ni], bv = cb[ni];
            tv += __shfl_xor(tv, 16); tv += __shfl_xor(tv, 32);
            bv += __shfl_xor(bv, 16); bv += __shfl_xor(bv, 32);
            if (lane < 16) {
                atomicAdd(&top[jgv[ni]], tv);
                atomicAdd(&bot[jgv[ni]], bv);
            }
        }
    }
}

// ============================================================================
// Kernel 3: loss = -mean(log((top+1e-9)/bot)); out pre-zeroed by normalize.
// ============================================================================
__global__ __launch_bounds__(256) void snnl_loss(
    const float* __restrict__ top, const float* __restrict__ bot,
    float* __restrict__ out)
{
    const int tid = (int)threadIdx.x;
    const int i   = (int)blockIdx.x * 256 + tid;
    float s = __logf((top[i] + 1e-9f) / bot[i]);
#pragma unroll
    for (int m = 32; m >= 1; m >>= 1) s += __shfl_xor(s, m);
    __shared__ float w4[4];
    if ((tid & 63) == 0) w4[tid >> 6] = s;
    __syncthreads();
    if (tid == 0)
        atomicAdd(out, -(w4[0] + w4[1] + w4[2] + w4[3]) * (1.0f / (float)NROWS));
}

// ============================================================================
extern "C" void kernel_launch(void* const* d_in, const int* in_sizes, int n_in,
                              void* d_out, int out_size, void* d_ws, size_t ws_size,
                              hipStream_t stream)
{
    const float* x = (const float*)d_in[0];
    const int*   y = (const int*)d_in[1];
    const float* T = (const float*)d_in[2];
    float* out = (float*)d_out;

    char* ws = (char*)d_ws;
    ushort_t* xn  = (ushort_t*)ws;                              // 16 MiB bf16 Xn
    float*    top = (float*)(ws + (size_t)16 * 1024 * 1024);    // 32 KiB
    float*    bot = top + NROWS;                                // 32 KiB

    snnl_normalize<<<NROWS, 256, 0, stream>>>(x, xn, top, bot, out);
    snnl_main<<<NTRI, 256, 0, stream>>>(xn, y, T, top, bot);
    snnl_loss<<<NROWS / 256, 256, 0, stream>>>(top, bot, out);
}